// Round 2
// baseline (226.078 us; speedup 1.0000x reference)
//
#include <hip/hip_runtime.h>

// Problem constants: A=1, B=8, M=256, H=2048, E=8, K=2, N=2048
#define Bn 8
#define Mn 256
#define Hn 2048
#define En 8
#define Kn 2
#define Nn 2048

// d_ws layout: hs[Bn*Hn] floats, then wsum[En*Hn] floats (128 KB total).
// No zero-init required: every element is written exactly once (no atomics).

// Fused reduction, hidden blocks FIRST so the 16.8 MB hidden stream overlaps
// the 134 MB gup stream instead of running in the tail:
//  blocks [0, 64):    hs[b,k] = sum_m hidden[0,b,m,k]   (b = bid>>3, ktile = bid&7)
//  blocks [64, 4160): one wave per (e,k) row of gate_up_proj -> wsum[e*H+k]
__global__ void reduce_kernel(const float* __restrict__ hidden,
                              const float* __restrict__ gup,
                              float* __restrict__ hs,
                              float* __restrict__ wsum) {
    const int bid = blockIdx.x;
    const int t   = threadIdx.x;
    if (bid < 64) {
        const int b  = bid >> 3;
        const int kt = bid & 7;
        const int k  = kt * 256 + t;            // 256 threads cover the k-tile
        const float* p = hidden + (size_t)b * Mn * Hn + k;
        float a0 = 0.f, a1 = 0.f, a2 = 0.f, a3 = 0.f;
#pragma unroll 4
        for (int m = 0; m < Mn; m += 4) {       // coalesced 1KB per row-step
            a0 += p[(size_t)(m + 0) * Hn];
            a1 += p[(size_t)(m + 1) * Hn];
            a2 += p[(size_t)(m + 2) * Hn];
            a3 += p[(size_t)(m + 3) * Hn];
        }
        hs[b * Hn + k] = (a0 + a1) + (a2 + a3); // single store, no atomics
    } else {
        // gate_up_proj row sums: row = e*H + k in [0, 16384); 4 waves/block
        const int wave = t >> 6;
        const int lane = t & 63;
        const int row  = (bid - 64) * 4 + wave;
        const float4* p = (const float4*)(gup + (size_t)row * Nn);
        float acc = 0.f;
#pragma unroll
        for (int i = 0; i < 8; ++i) {
            float4 v = p[i * 64 + lane];        // 64 lanes x 16B = 1KB per step
            acc += (v.x + v.y) + (v.z + v.w);
        }
#pragma unroll
        for (int off = 32; off > 0; off >>= 1)
            acc += __shfl_down(acc, off, 64);
        if (lane == 0) wsum[row] = acc;
    }
}

// out = sum_{b,e,k} sp[b,e] * hs[b,k] * wsum[e,k]   (single block)
__global__ void final_kernel(const float* __restrict__ sparsity,
                             const float* __restrict__ hs,
                             const float* __restrict__ wsum,
                             float* __restrict__ out) {
    __shared__ float sp[Bn][En];
    __shared__ float red[4];
    const int t = threadIdx.x;
    if (t < Bn * En) {
        const int b = t >> 3, e = t & 7;
        sp[b][e] = sparsity[b * (Kn * En) + e];   // sparsity[0, b, 0, e]
    }
    __syncthreads();
    float acc = 0.f;
    for (int k = t; k < Hn; k += 256) {
        float h[Bn];
#pragma unroll
        for (int b = 0; b < Bn; ++b) h[b] = hs[b * Hn + k];
#pragma unroll
        for (int e = 0; e < En; ++e) {
            float g = 0.f;
#pragma unroll
            for (int b = 0; b < Bn; ++b) g += sp[b][e] * h[b];
            acc += wsum[e * Hn + k] * g;
        }
    }
#pragma unroll
    for (int off = 32; off > 0; off >>= 1)
        acc += __shfl_down(acc, off, 64);
    const int lane = t & 63, wave = t >> 6;
    if (lane == 0) red[wave] = acc;
    __syncthreads();
    if (t == 0) out[0] = red[0] + red[1] + red[2] + red[3];
}

extern "C" void kernel_launch(void* const* d_in, const int* in_sizes, int n_in,
                              void* d_out, int out_size, void* d_ws, size_t ws_size,
                              hipStream_t stream) {
    const float* hidden   = (const float*)d_in[0];  // (1,8,256,2048) fp32
    const float* sparsity = (const float*)d_in[1];  // (1,8,2,8) fp32
    const float* gup      = (const float*)d_in[2];  // (1,8,2048,2048) fp32

    float* hs   = (float*)d_ws;          // Bn*Hn floats
    float* wsum = hs + Bn * Hn;          // En*Hn floats

    reduce_kernel<<<64 + 4096, 256, 0, stream>>>(hidden, gup, hs, wsum);
    final_kernel<<<1, 256, 0, stream>>>(sparsity, hs, wsum, (float*)d_out);
}

// Round 4
// 214.487 us; speedup vs baseline: 1.0540x; 1.0540x over previous
//
#include <hip/hip_runtime.h>

// Problem constants: A=1, B=8, M=256, H=2048, E=8, K=2, N=2048
#define Bn 8
#define Mn 256
#define Hn 2048
#define En 8
#define Kn 2
#define Nn 2048

// d_ws layout:
//   partial[Bn][8][Hn]  floats (512 KB)  -- hidden m-chunk partial sums
//   wsum  [En][Hn]      floats (64 KB)   -- gate_up_proj row sums
// Every element written exactly once -> no atomics, no zero-init.

// blocks [0, 1024):   hidden partial sums. block = (b, mc, kh):
//                     b=bid>>7, mc=(bid>>4)&7 (32 m-rows), kh=bid&15 (128-k slice)
//                     16 slices x 128 = full Hn=2048 coverage (round-3 bug: had 8).
//                     thread: col=t&31 (float4 col), tg=t>>5 (4 m-rows) ->
//                     4 independent float4 loads, LDS-reduce 8 partials/col.
// blocks [1024, 5120): gup row sums, one wave per (e,k) row, 8 float4 loads
//                     issued before any adds (force MLP).
__global__ void reduce_kernel(const float* __restrict__ hidden,
                              const float* __restrict__ gup,
                              float* __restrict__ partial,
                              float* __restrict__ wsum) {
    const int bid = blockIdx.x;
    const int t   = threadIdx.x;
    if (bid < 1024) {
        const int b  = bid >> 7;
        const int mc = (bid >> 4) & 7;
        const int kh = bid & 15;
        const int col = t & 31;           // float4 column within 128-float slice
        const int tg  = t >> 5;           // m-group of 4
        const int m0  = mc * 32 + tg * 4;
        const float4* hp = (const float4*)(hidden + ((size_t)b * Mn + m0) * Hn + kh * 128);
        // 4 independent loads, shallow chain
        float4 v0 = hp[0 * (Hn / 4) + col];
        float4 v1 = hp[1 * (Hn / 4) + col];
        float4 v2 = hp[2 * (Hn / 4) + col];
        float4 v3 = hp[3 * (Hn / 4) + col];
        float4 s;
        s.x = (v0.x + v1.x) + (v2.x + v3.x);
        s.y = (v0.y + v1.y) + (v2.y + v3.y);
        s.z = (v0.z + v1.z) + (v2.z + v3.z);
        s.w = (v0.w + v1.w) + (v2.w + v3.w);
        __shared__ float4 sd[8][32];
        sd[tg][col] = s;
        __syncthreads();
        if (t < 32) {
            float4 r = sd[0][t];
#pragma unroll
            for (int g = 1; g < 8; ++g) {
                float4 q = sd[g][t];
                r.x += q.x; r.y += q.y; r.z += q.z; r.w += q.w;
            }
            ((float4*)partial)[(size_t)(b * 8 + mc) * (Hn / 4) + kh * 32 + t] = r;
        }
    } else {
        // gate_up_proj row sums: row = e*H + k in [0, 16384); 4 waves/block
        const int wave = t >> 6;
        const int lane = t & 63;
        const int row  = (bid - 1024) * 4 + wave;
        const float4* p = (const float4*)(gup + (size_t)row * Nn);
        // force 8 outstanding float4 loads before any accumulation
        float4 v0 = p[0 * 64 + lane];
        float4 v1 = p[1 * 64 + lane];
        float4 v2 = p[2 * 64 + lane];
        float4 v3 = p[3 * 64 + lane];
        float4 v4 = p[4 * 64 + lane];
        float4 v5 = p[5 * 64 + lane];
        float4 v6 = p[6 * 64 + lane];
        float4 v7 = p[7 * 64 + lane];
        float s01 = (v0.x + v0.y + v0.z + v0.w) + (v1.x + v1.y + v1.z + v1.w);
        float s23 = (v2.x + v2.y + v2.z + v2.w) + (v3.x + v3.y + v3.z + v3.w);
        float s45 = (v4.x + v4.y + v4.z + v4.w) + (v5.x + v5.y + v5.z + v5.w);
        float s67 = (v6.x + v6.y + v6.z + v6.w) + (v7.x + v7.y + v7.z + v7.w);
        float acc = (s01 + s23) + (s45 + s67);
#pragma unroll
        for (int off = 32; off > 0; off >>= 1)
            acc += __shfl_down(acc, off, 64);
        if (lane == 0) wsum[row] = acc;
    }
}

// out = sum_{b,e,k} sp[b,e] * (sum_mc partial[b,mc,k]) * wsum[e,k]
// single block, 1024 threads (16 waves)
__global__ void final_kernel(const float* __restrict__ sparsity,
                             const float* __restrict__ partial,
                             const float* __restrict__ wsum,
                             float* __restrict__ out) {
    __shared__ float sp[Bn][En];
    __shared__ float red[16];
    const int t = threadIdx.x;
    if (t < Bn * En) {
        const int b = t >> 3, e = t & 7;
        sp[b][e] = sparsity[b * (Kn * En) + e];   // sparsity[0, b, 0, e]
    }
    __syncthreads();
    float acc = 0.f;
    for (int k = t; k < Hn; k += 1024) {
        float h[Bn];
#pragma unroll
        for (int b = 0; b < Bn; ++b) {
            float hb = 0.f;
#pragma unroll
            for (int mc = 0; mc < 8; ++mc)
                hb += partial[(size_t)(b * 8 + mc) * Hn + k];
            h[b] = hb;
        }
#pragma unroll
        for (int e = 0; e < En; ++e) {
            float g = 0.f;
#pragma unroll
            for (int b = 0; b < Bn; ++b) g += sp[b][e] * h[b];
            acc += wsum[e * Hn + k] * g;
        }
    }
#pragma unroll
    for (int off = 32; off > 0; off >>= 1)
        acc += __shfl_down(acc, off, 64);
    const int lane = t & 63, wave = t >> 6;
    if (lane == 0) red[wave] = acc;
    __syncthreads();
    if (t == 0) {
        float r = 0.f;
#pragma unroll
        for (int w = 0; w < 16; ++w) r += red[w];
        out[0] = r;
    }
}

extern "C" void kernel_launch(void* const* d_in, const int* in_sizes, int n_in,
                              void* d_out, int out_size, void* d_ws, size_t ws_size,
                              hipStream_t stream) {
    const float* hidden   = (const float*)d_in[0];  // (1,8,256,2048) fp32
    const float* sparsity = (const float*)d_in[1];  // (1,8,2,8) fp32
    const float* gup      = (const float*)d_in[2];  // (1,8,2048,2048) fp32

    float* partial = (float*)d_ws;                  // 8*8*2048 floats (512 KB)
    float* wsum    = partial + Bn * 8 * Hn;         // 8*2048 floats (64 KB)

    reduce_kernel<<<1024 + 4096, 256, 0, stream>>>(hidden, gup, partial, wsum);
    final_kernel<<<1, 1024, 0, stream>>>(sparsity, partial, wsum, (float*)d_out);
}

// Round 5
// 205.264 us; speedup vs baseline: 1.1014x; 1.0449x over previous
//
#include <hip/hip_runtime.h>

// Problem constants: A=1, B=8, M=256, H=2048, E=8, K=2, N=2048
#define Bn 8
#define Mn 256
#define Hn 2048
#define En 8
#define Kn 2
#define Nn 2048

// d_ws layout:
//   hs  [Bn][Hn] floats (64 KB) -- hidden column sums   (write-once, no init)
//   wsum[En][Hn] floats (64 KB) -- gate_up_proj row sums (write-once, no init)

// blocks [0, 128):    hidden full-column sums -> hs[b*Hn + k], no partial table.
//                     block = (b = bid>>4, kh = bid&15 -> 128-float k-slice).
//                     thread: col=t&31 (float4 col), mg=t>>5 (owns 32 m-rows).
//                     32 stride-8KB float4 loads, unrolled, 4 indep accumulators;
//                     LDS-fold of the 8 m-groups, single float4 store.
// blocks [128, 2176): gup row sums, TWO rows per wave, 16 float4 loads issued
//                     before any accumulation (256 B/lane MLP, longer-lived waves).
__global__ void reduce_kernel(const float* __restrict__ hidden,
                              const float* __restrict__ gup,
                              float* __restrict__ hs,
                              float* __restrict__ wsum) {
    const int bid = blockIdx.x;
    const int t   = threadIdx.x;
    if (bid < 128) {
        const int b   = bid >> 4;
        const int kh  = bid & 15;
        const int col = t & 31;          // float4 column within 128-float slice
        const int mg  = t >> 5;          // m-group: 32 rows each
        const float4* hp = (const float4*)(hidden + ((size_t)b * Mn + mg * 32) * Hn)
                           + kh * 32 + col;
        float4 a0 = {0,0,0,0}, a1 = {0,0,0,0}, a2 = {0,0,0,0}, a3 = {0,0,0,0};
#pragma unroll
        for (int m = 0; m < 32; m += 4) {          // 32 independent loads visible
            float4 v0 = hp[(size_t)(m + 0) * (Hn / 4)];
            float4 v1 = hp[(size_t)(m + 1) * (Hn / 4)];
            float4 v2 = hp[(size_t)(m + 2) * (Hn / 4)];
            float4 v3 = hp[(size_t)(m + 3) * (Hn / 4)];
            a0.x += v0.x; a0.y += v0.y; a0.z += v0.z; a0.w += v0.w;
            a1.x += v1.x; a1.y += v1.y; a1.z += v1.z; a1.w += v1.w;
            a2.x += v2.x; a2.y += v2.y; a2.z += v2.z; a2.w += v2.w;
            a3.x += v3.x; a3.y += v3.y; a3.z += v3.z; a3.w += v3.w;
        }
        float4 s;
        s.x = (a0.x + a1.x) + (a2.x + a3.x);
        s.y = (a0.y + a1.y) + (a2.y + a3.y);
        s.z = (a0.z + a1.z) + (a2.z + a3.z);
        s.w = (a0.w + a1.w) + (a2.w + a3.w);
        __shared__ float4 sd[8][32];
        sd[mg][col] = s;
        __syncthreads();
        if (t < 32) {
            float4 r = sd[0][t];
#pragma unroll
            for (int g = 1; g < 8; ++g) {
                float4 q = sd[g][t];
                r.x += q.x; r.y += q.y; r.z += q.z; r.w += q.w;
            }
            ((float4*)hs)[(size_t)b * (Hn / 4) + kh * 32 + t] = r;
        }
    } else {
        // gup row sums: wave w handles rows 2w and 2w+1; row = e*Hn + k
        const int wave = (bid - 128) * 4 + (t >> 6);
        const int lane = t & 63;
        const int r0 = wave * 2;
        const float4* p0 = (const float4*)(gup + (size_t)r0 * Nn);
        const float4* p1 = (const float4*)(gup + (size_t)(r0 + 1) * Nn);
        // 16 loads in flight before any consumption
        float4 u0 = p0[0 * 64 + lane], u1 = p0[1 * 64 + lane];
        float4 u2 = p0[2 * 64 + lane], u3 = p0[3 * 64 + lane];
        float4 u4 = p0[4 * 64 + lane], u5 = p0[5 * 64 + lane];
        float4 u6 = p0[6 * 64 + lane], u7 = p0[7 * 64 + lane];
        float4 w0 = p1[0 * 64 + lane], w1 = p1[1 * 64 + lane];
        float4 w2 = p1[2 * 64 + lane], w3 = p1[3 * 64 + lane];
        float4 w4 = p1[4 * 64 + lane], w5 = p1[5 * 64 + lane];
        float4 w6 = p1[6 * 64 + lane], w7 = p1[7 * 64 + lane];
        float sa = ((u0.x + u0.y + u0.z + u0.w) + (u1.x + u1.y + u1.z + u1.w))
                 + ((u2.x + u2.y + u2.z + u2.w) + (u3.x + u3.y + u3.z + u3.w))
                 + ((u4.x + u4.y + u4.z + u4.w) + (u5.x + u5.y + u5.z + u5.w))
                 + ((u6.x + u6.y + u6.z + u6.w) + (u7.x + u7.y + u7.z + u7.w));
        float sb = ((w0.x + w0.y + w0.z + w0.w) + (w1.x + w1.y + w1.z + w1.w))
                 + ((w2.x + w2.y + w2.z + w2.w) + (w3.x + w3.y + w3.z + w3.w))
                 + ((w4.x + w4.y + w4.z + w4.w) + (w5.x + w5.y + w5.z + w5.w))
                 + ((w6.x + w6.y + w6.z + w6.w) + (w7.x + w7.y + w7.z + w7.w));
#pragma unroll
        for (int off = 32; off > 0; off >>= 1) {
            sa += __shfl_down(sa, off, 64);
            sb += __shfl_down(sb, off, 64);
        }
        if (lane == 0) {
            wsum[r0]     = sa;
            wsum[r0 + 1] = sb;
        }
    }
}

// out = sum_{b,e,k} sp[b,e] * hs[b,k] * wsum[e,k]   (single block, 256 threads,
// reads only 128 KB)
__global__ void final_kernel(const float* __restrict__ sparsity,
                             const float* __restrict__ hs,
                             const float* __restrict__ wsum,
                             float* __restrict__ out) {
    __shared__ float sp[Bn][En];
    __shared__ float red[4];
    const int t = threadIdx.x;
    if (t < Bn * En) {
        const int b = t >> 3, e = t & 7;
        sp[b][e] = sparsity[b * (Kn * En) + e];   // sparsity[0, b, 0, e]
    }
    __syncthreads();
    float acc = 0.f;
#pragma unroll
    for (int i = 0; i < Hn / 256; ++i) {
        const int k = i * 256 + t;
        float h[Bn];
#pragma unroll
        for (int b = 0; b < Bn; ++b) h[b] = hs[b * Hn + k];
#pragma unroll
        for (int e = 0; e < En; ++e) {
            float g = 0.f;
#pragma unroll
            for (int b = 0; b < Bn; ++b) g += sp[b][e] * h[b];
            acc += wsum[e * Hn + k] * g;
        }
    }
#pragma unroll
    for (int off = 32; off > 0; off >>= 1)
        acc += __shfl_down(acc, off, 64);
    const int lane = t & 63, wave = t >> 6;
    if (lane == 0) red[wave] = acc;
    __syncthreads();
    if (t == 0) out[0] = (red[0] + red[1]) + (red[2] + red[3]);
}

extern "C" void kernel_launch(void* const* d_in, const int* in_sizes, int n_in,
                              void* d_out, int out_size, void* d_ws, size_t ws_size,
                              hipStream_t stream) {
    const float* hidden   = (const float*)d_in[0];  // (1,8,256,2048) fp32
    const float* sparsity = (const float*)d_in[1];  // (1,8,2,8) fp32
    const float* gup      = (const float*)d_in[2];  // (1,8,2048,2048) fp32

    float* hs   = (float*)d_ws;          // Bn*Hn floats (64 KB)
    float* wsum = hs + Bn * Hn;          // En*Hn floats (64 KB)

    reduce_kernel<<<128 + 2048, 256, 0, stream>>>(hidden, gup, hs, wsum);
    final_kernel<<<1, 256, 0, stream>>>(sparsity, hs, wsum, (float*)d_out);
}

// Round 6
// 190.195 us; speedup vs baseline: 1.1887x; 1.0792x over previous
//
#include <hip/hip_runtime.h>

// Problem constants: A=1, B=8, M=256, H=2048, E=8, K=2, N=2048
#define Bn 8
#define Mn 256
#define Hn 2048
#define En 8
#define Kn 2
#define Nn 2048

typedef float vf4 __attribute__((ext_vector_type(4)));

// d_ws layout:
//   hs  [Bn][Hn] floats (64 KB) -- hidden column sums   (write-once, no init)
//   wsum[En][Hn] floats (64 KB) -- gate_up_proj row sums (write-once, no init)

// blocks [0, 128):    hidden full-column sums -> hs[b*Hn + k]  (R5 design).
// blocks [128, 1152): gup row sums. Persistent pipelined waves: 4096 waves,
//                     each owns 4 consecutive rows; prefetch row j+1's 8
//                     float4 loads while consuming row j -> load queue never
//                     drains until the last row. Nontemporal (single-use).
__global__ void reduce_kernel(const float* __restrict__ hidden,
                              const float* __restrict__ gup,
                              float* __restrict__ hs,
                              float* __restrict__ wsum) {
    const int bid = blockIdx.x;
    const int t   = threadIdx.x;
    if (bid < 128) {
        const int b   = bid >> 4;
        const int kh  = bid & 15;
        const int col = t & 31;          // float4 column within 128-float slice
        const int mg  = t >> 5;          // m-group: 32 rows each
        const vf4* hp = (const vf4*)(hidden + ((size_t)b * Mn + mg * 32) * Hn)
                        + kh * 32 + col;
        vf4 a0 = 0.f, a1 = 0.f, a2 = 0.f, a3 = 0.f;
#pragma unroll
        for (int m = 0; m < 32; m += 4) {
            vf4 v0 = __builtin_nontemporal_load(hp + (size_t)(m + 0) * (Hn / 4));
            vf4 v1 = __builtin_nontemporal_load(hp + (size_t)(m + 1) * (Hn / 4));
            vf4 v2 = __builtin_nontemporal_load(hp + (size_t)(m + 2) * (Hn / 4));
            vf4 v3 = __builtin_nontemporal_load(hp + (size_t)(m + 3) * (Hn / 4));
            a0 += v0; a1 += v1; a2 += v2; a3 += v3;
        }
        vf4 s = (a0 + a1) + (a2 + a3);
        __shared__ vf4 sd[8][32];
        sd[mg][col] = s;
        __syncthreads();
        if (t < 32) {
            vf4 r = sd[0][t];
#pragma unroll
            for (int g = 1; g < 8; ++g) r += sd[g][t];
            ((vf4*)hs)[(size_t)b * (Hn / 4) + kh * 32 + t] = r;
        }
    } else {
        // 4096 waves; wave w handles rows [4w, 4w+4); row = e*Hn + k index
        const int wave = (bid - 128) * 4 + (t >> 6);
        const int lane = t & 63;
        const size_t r0 = (size_t)wave * 4;
        const vf4* base = (const vf4*)gup;   // row r starts at base + r*512
        vf4 cur[8], nxt[8];
#pragma unroll
        for (int i = 0; i < 8; ++i)
            cur[i] = __builtin_nontemporal_load(base + r0 * 512 + i * 64 + lane);
        float rowsum[4];
#pragma unroll
        for (int j = 0; j < 4; ++j) {
            if (j < 3) {
#pragma unroll
                for (int i = 0; i < 8; ++i)
                    nxt[i] = __builtin_nontemporal_load(
                        base + (r0 + j + 1) * 512 + i * 64 + lane);
            }
            vf4 v = ((cur[0] + cur[1]) + (cur[2] + cur[3]))
                  + ((cur[4] + cur[5]) + (cur[6] + cur[7]));
            float s = (v.x + v.y) + (v.z + v.w);
#pragma unroll
            for (int off = 32; off > 0; off >>= 1)
                s += __shfl_down(s, off, 64);
            rowsum[j] = s;                 // valid on lane 0
            if (j < 3) {
#pragma unroll
                for (int i = 0; i < 8; ++i) cur[i] = nxt[i];
            }
        }
        if (lane == 0) {
            vf4 o = { rowsum[0], rowsum[1], rowsum[2], rowsum[3] };
            ((vf4*)wsum)[wave] = o;        // rows 4w..4w+3 contiguous
        }
    }
}

// out = sum_{b,e,k} sp[b,e] * hs[b,k] * wsum[e,k]   (single block, 256 threads,
// reads only 128 KB)
__global__ void final_kernel(const float* __restrict__ sparsity,
                             const float* __restrict__ hs,
                             const float* __restrict__ wsum,
                             float* __restrict__ out) {
    __shared__ float sp[Bn][En];
    __shared__ float red[4];
    const int t = threadIdx.x;
    if (t < Bn * En) {
        const int b = t >> 3, e = t & 7;
        sp[b][e] = sparsity[b * (Kn * En) + e];   // sparsity[0, b, 0, e]
    }
    __syncthreads();
    float acc = 0.f;
#pragma unroll
    for (int i = 0; i < Hn / 256; ++i) {
        const int k = i * 256 + t;
        float h[Bn];
#pragma unroll
        for (int b = 0; b < Bn; ++b) h[b] = hs[b * Hn + k];
#pragma unroll
        for (int e = 0; e < En; ++e) {
            float g = 0.f;
#pragma unroll
            for (int b = 0; b < Bn; ++b) g += sp[b][e] * h[b];
            acc += wsum[e * Hn + k] * g;
        }
    }
#pragma unroll
    for (int off = 32; off > 0; off >>= 1)
        acc += __shfl_down(acc, off, 64);
    const int lane = t & 63, wave = t >> 6;
    if (lane == 0) red[wave] = acc;
    __syncthreads();
    if (t == 0) out[0] = (red[0] + red[1]) + (red[2] + red[3]);
}

extern "C" void kernel_launch(void* const* d_in, const int* in_sizes, int n_in,
                              void* d_out, int out_size, void* d_ws, size_t ws_size,
                              hipStream_t stream) {
    const float* hidden   = (const float*)d_in[0];  // (1,8,256,2048) fp32
    const float* sparsity = (const float*)d_in[1];  // (1,8,2,8) fp32
    const float* gup      = (const float*)d_in[2];  // (1,8,2048,2048) fp32

    float* hs   = (float*)d_ws;          // Bn*Hn floats (64 KB)
    float* wsum = hs + Bn * Hn;          // En*Hn floats (64 KB)

    reduce_kernel<<<128 + 1024, 256, 0, stream>>>(hidden, gup, hs, wsum);
    final_kernel<<<1, 256, 0, stream>>>(sparsity, hs, wsum, (float*)d_out);
}